// Round 22
// baseline (114.367 us; speedup 1.0000x reference)
//
#include <hip/hip_runtime.h>
#include <hip/hip_bf16.h>

#define B_  2
#define N_  2048
#define E_  1024
#define H_  16
#define HD_ 64
#define M_  (B_*N_)
#define RSZ ((size_t)M_ * E_)          // one ws region, u16 elems (8 MB)

// Q pre-scale: 1/sqrt(64) * log2(e)  -> scores land in log2 domain
#define QSCALE 0.18033688f
// defer-max threshold in log2 units (= 8 nats)
#define THR2   11.5416f

typedef short bf16x8 __attribute__((ext_vector_type(8)));
typedef float f32x4 __attribute__((ext_vector_type(4)));
typedef unsigned short u16x8 __attribute__((ext_vector_type(8)));

#define AS1 __attribute__((address_space(1)))
#define AS3 __attribute__((address_space(3)))

__device__ __forceinline__ unsigned short f2bfu(float f) {
    __hip_bfloat16 h = __float2bfloat16(f);
    return *reinterpret_cast<unsigned short*>(&h);
}
__device__ __forceinline__ unsigned int cvtpk(float lo, float hi) {
    unsigned int r;
    asm("v_cvt_pk_bf16_f32 %0, %1, %2" : "=v"(r) : "v"(lo), "v"(hi));
    return r;
}
__device__ __forceinline__ float exp2i(float x) {   // 2^x, single v_exp_f32
    float r;
    asm("v_exp_f32 %0, %1" : "=v"(r) : "v"(x));
    return r;
}
__device__ __forceinline__ float max3f(float a, float b, float c) {
    float r;
    asm("v_max3_f32 %0, %1, %2, %3" : "=v"(r) : "v"(a), "v"(b), "v"(c));
    return r;
}
#define MFMA16(a,b,c) __builtin_amdgcn_mfma_f32_16x16x32_bf16((a),(b),(c),0,0,0)

__device__ __forceinline__ void gl_lds16(const void* g, void* l) {
    __builtin_amdgcn_global_load_lds((const AS1 void*)g, (AS3 void*)l, 16, 0, 0);
}

// ---------------------------------------------------------------------------
// Kernel 0a: fused fp32->bf16 conversion for x + Wq,Wk,Wv,Wo in ONE launch.
// ---------------------------------------------------------------------------
__global__ __launch_bounds__(256) void fconv_all_kernel(
    const float* __restrict__ x,
    const float* __restrict__ Wq, const float* __restrict__ Wk,
    const float* __restrict__ Wv, const float* __restrict__ Wo,
    unsigned short* __restrict__ xbf, unsigned short* __restrict__ wbf)
{
    const int bid = blockIdx.x;
    const float* src;
    unsigned short* dst;
    int off;
    if (bid < 2048) {
        src = x; dst = xbf; off = bid * 2048 + threadIdx.x * 8;
    } else {
        const int z = (bid - 2048) >> 9;             // 0..3
        src = (z == 0) ? Wq : (z == 1 ? Wk : (z == 2 ? Wv : Wo));
        dst = wbf + (size_t)z * E_ * E_;
        off = ((bid - 2048) & 511) * 2048 + threadIdx.x * 8;
    }
    const float4 a = *reinterpret_cast<const float4*>(src + off);
    const float4 b = *reinterpret_cast<const float4*>(src + off + 4);
    u16x8 v;
    v[0]=f2bfu(a.x); v[1]=f2bfu(a.y); v[2]=f2bfu(a.z); v[3]=f2bfu(a.w);
    v[4]=f2bfu(b.x); v[5]=f2bfu(b.y); v[6]=f2bfu(b.z); v[7]=f2bfu(b.w);
    *reinterpret_cast<u16x8*>(dst + off) = v;
}

// Kernel 0b: single-source conversion (fallback path only)
__global__ __launch_bounds__(256) void fconv_kernel(
    const float* __restrict__ src, unsigned short* __restrict__ dst)
{
    const int i0 = (blockIdx.x * 256 + threadIdx.x) * 8;
    const float4 a = *reinterpret_cast<const float4*>(src + i0);
    const float4 b = *reinterpret_cast<const float4*>(src + i0 + 4);
    u16x8 v;
    v[0]=f2bfu(a.x); v[1]=f2bfu(a.y); v[2]=f2bfu(a.z); v[3]=f2bfu(a.w);
    v[4]=f2bfu(b.x); v[5]=f2bfu(b.y); v[6]=f2bfu(b.z); v[7]=f2bfu(b.w);
    *reinterpret_cast<u16x8*>(dst + i0) = v;
}

// ---------------------------------------------------------------------------
// Kernel 1a (main): Z-FUSED QKV projection, 64x128x3z tile with A-operand in
// REGISTERS (one-step prefetch; each wave's A-frags are wave-private so LDS
// buys nothing). LDS = 3 B tiles = 48 KB -> 3 blocks/CU (was 2 at 56 KB).
// Work/barrier unchanged: 48 MFMA/wave/K-step. XOR-swizzled glds B staging.
// Q pre-scaled by QSCALE (log2-domain). z==2 writes V^T.
// ---------------------------------------------------------------------------
__global__ __launch_bounds__(256) void qkv_fused_kernel(
    const unsigned short* __restrict__ xbf, const unsigned short* __restrict__ wbf,
    unsigned short* __restrict__ qkv)
{
    const int m0 = blockIdx.x * 64;
    const int n0 = blockIdx.y * 128;
    __shared__ unsigned short ldsB[3][128*64];    // 48 KB
    const int t = threadIdx.x;
    const int lane = t & 63;
    const int w = t >> 6, wr = w >> 1, wc = w & 1;
    const int fr = lane & 15, fq = lane >> 4;
    const int subrow = lane >> 3;                    // 0..7
    const int csw = ((lane & 7) ^ subrow) * 8;       // inverse-swizzled src col
    const int rcol = ((fq * 8) ^ ((fr & 7) * 8));    // swizzled read col (ks=0)
    f32x4 acc[3][2][4] = {};

    // A-row base pointers for this lane's two m-fragments (wave-private rows)
    const unsigned short* arow0 = xbf + (size_t)(m0 + wr*32 + fr) * E_;
    const unsigned short* arow1 = xbf + (size_t)(m0 + wr*32 + 16 + fr) * E_;

    bf16x8 ar[2][2];                                 // [mf][ks] current A frags
    #pragma unroll
    for (int ks = 0; ks < 2; ++ks) {
        ar[0][ks] = *reinterpret_cast<const bf16x8*>(arow0 + ks*32 + fq*8);
        ar[1][ks] = *reinterpret_cast<const bf16x8*>(arow1 + ks*32 + fq*8);
    }

    for (int kt = 0; kt < 16; ++kt) {
        const int k0 = kt * 64;
        __syncthreads();                             // prev compute done
        #pragma unroll
        for (int i = 0; i < 12; ++i) {               // 48 B-chunks over 4 waves
            const int c = w * 12 + i;
            const int zb = c >> 4, bc = c & 15;
            const int row = bc * 8 + subrow;
            gl_lds16(wbf + (size_t)zb * E_ * E_ + (size_t)(n0 + row) * E_ + k0 + csw,
                     &ldsB[zb][bc * 512]);
        }
        __syncthreads();                             // stage visible
        bf16x8 an[2][2];
        if (kt + 1 < 16) {                           // prefetch next A frags
            #pragma unroll
            for (int ks = 0; ks < 2; ++ks) {
                an[0][ks] = *reinterpret_cast<const bf16x8*>(arow0 + k0 + 64 + ks*32 + fq*8);
                an[1][ks] = *reinterpret_cast<const bf16x8*>(arow1 + k0 + 64 + ks*32 + fq*8);
            }
        }
        #pragma unroll
        for (int ks = 0; ks < 2; ++ks) {
            #pragma unroll
            for (int zb = 0; zb < 3; ++zb) {
                bf16x8 bfv[4];
                #pragma unroll
                for (int nf = 0; nf < 4; ++nf)
                    bfv[nf] = *(const bf16x8*)&ldsB[zb][(wc*64 + nf*16 + fr)*64 + (rcol ^ (ks*32))];
                #pragma unroll
                for (int mf = 0; mf < 2; ++mf)
                    #pragma unroll
                    for (int nf = 0; nf < 4; ++nf)
                        acc[zb][mf][nf] = MFMA16(ar[mf][ks], bfv[nf], acc[zb][mf][nf]);
            }
        }
        if (kt + 1 < 16) {
            #pragma unroll
            for (int ks = 0; ks < 2; ++ks) {
                ar[0][ks] = an[0][ks];
                ar[1][ks] = an[1][ks];
            }
        }
    }

    #pragma unroll
    for (int zb = 0; zb < 3; ++zb) {
        unsigned short* __restrict__ out = qkv + (size_t)zb * RSZ;
        const float scale = (zb == 0) ? QSCALE : 1.0f;
        #pragma unroll
        for (int mf = 0; mf < 2; ++mf) {
            #pragma unroll
            for (int r = 0; r < 4; ++r) {
                const int m = m0 + wr*32 + mf*16 + fq*4 + r;
                const int b = m >> 11, npos = m & (N_ - 1);
                #pragma unroll
                for (int nf = 0; nf < 4; ++nf) {
                    const int n = n0 + wc*64 + nf*16 + fr;
                    const int h = n >> 6, d = n & 63;
                    const unsigned short val = f2bfu(acc[zb][mf][nf][r] * scale);
                    if (zb == 2)   // V^T: [bh][d][npos]
                        out[(((size_t)(b*H_ + h))*HD_ + d)*N_ + npos] = val;
                    else
                        out[(((size_t)(b*H_ + h))*N_ + npos)*HD_ + d] = val;
                }
            }
        }
    }
}

// ---------------------------------------------------------------------------
// Kernel 1b (fallback): QKV with fp32 x converted at staging (reg-staged).
// ---------------------------------------------------------------------------
__global__ __launch_bounds__(256) void qkv_f32_kernel(
    const float* __restrict__ x, const unsigned short* __restrict__ wbf,
    unsigned short* __restrict__ qkv)
{
    const int z = blockIdx.z;
    const unsigned short* __restrict__ W = wbf + (size_t)z * E_ * E_;
    unsigned short* __restrict__ out = qkv + (size_t)z * RSZ;
    const int m0 = blockIdx.x * 128;
    const int n0 = blockIdx.y * 128;
    __shared__ unsigned short As[128][72];
    __shared__ unsigned short Bs[128][72];
    const int t = threadIdx.x;
    const int lane = t & 63;
    const int w = t >> 6, wr = w >> 1, wc = w & 1;
    const int fr = lane & 15, fq = lane >> 4;
    const int srow = t >> 1, scol = (t & 1) * 32;
    f32x4 acc[4][4] = {};

    const float* arow = x + (size_t)(m0 + srow) * E_ + scol;
    const unsigned short* brow = W + (size_t)(n0 + srow) * E_ + scol;

    float4 a4[8];
    u16x8 b8[4];
    #pragma unroll
    for (int i = 0; i < 8; ++i) a4[i] = reinterpret_cast<const float4*>(arow)[i];
    #pragma unroll
    for (int i = 0; i < 4; ++i) b8[i] = reinterpret_cast<const u16x8*>(brow)[i];

    for (int k0 = 0; k0 < E_; k0 += 64) {
        __syncthreads();
        #pragma unroll
        for (int j = 0; j < 4; ++j) {
            u16x8 va;
            va[0]=f2bfu(a4[2*j].x); va[1]=f2bfu(a4[2*j].y); va[2]=f2bfu(a4[2*j].z); va[3]=f2bfu(a4[2*j].w);
            va[4]=f2bfu(a4[2*j+1].x); va[5]=f2bfu(a4[2*j+1].y); va[6]=f2bfu(a4[2*j+1].z); va[7]=f2bfu(a4[2*j+1].w);
            *reinterpret_cast<u16x8*>(&As[srow][scol + 8*j]) = va;
            *reinterpret_cast<u16x8*>(&Bs[srow][scol + 8*j]) = b8[j];
        }
        __syncthreads();
        if (k0 + 64 < E_) {
            #pragma unroll
            for (int i = 0; i < 8; ++i)
                a4[i] = reinterpret_cast<const float4*>(arow + k0 + 64)[i];
            #pragma unroll
            for (int i = 0; i < 4; ++i)
                b8[i] = reinterpret_cast<const u16x8*>(brow + k0 + 64)[i];
        }
        #pragma unroll
        for (int ks = 0; ks < 2; ++ks) {
            bf16x8 af[4], bfv[4];
            #pragma unroll
            for (int mf = 0; mf < 4; ++mf)
                af[mf] = *reinterpret_cast<const bf16x8*>(&As[wr*64 + mf*16 + fr][ks*32 + fq*8]);
            #pragma unroll
            for (int nf = 0; nf < 4; ++nf)
                bfv[nf] = *reinterpret_cast<const bf16x8*>(&Bs[wc*64 + nf*16 + fr][ks*32 + fq*8]);
            #pragma unroll
            for (int mf = 0; mf < 4; ++mf)
                #pragma unroll
                for (int nf = 0; nf < 4; ++nf)
                    acc[mf][nf] = MFMA16(af[mf], bfv[nf], acc[mf][nf]);
        }
    }

    const float scale = (z == 0) ? QSCALE : 1.0f;
    #pragma unroll
    for (int mf = 0; mf < 4; ++mf) {
        #pragma unroll
        for (int r = 0; r < 4; ++r) {
            const int m = m0 + wr*64 + mf*16 + fq*4 + r;
            const int b = m >> 11, npos = m & (N_ - 1);
            #pragma unroll
            for (int nf = 0; nf < 4; ++nf) {
                const int n = n0 + wc*64 + nf*16 + fr;
                const int h = n >> 6, d = n & 63;
                const unsigned short val = f2bfu(acc[mf][nf][r] * scale);
                if (z == 2)
                    out[(((size_t)(b*H_ + h))*HD_ + d)*N_ + npos] = val;
                else
                    out[(((size_t)(b*H_ + h))*N_ + npos)*HD_ + d] = val;
            }
        }
    }
}

// ---------------------------------------------------------------------------
// Kernel 2: MFMA flash attention — R19/R20 structure (dbuf, 1 barrier/tile,
// pairing, exp2-domain softmax, max3 row-max). Unchanged.
// ---------------------------------------------------------------------------
__global__ __launch_bounds__(512) void attn_mfma_kernel(
    const unsigned short* __restrict__ qkv, unsigned short* __restrict__ attn_out)
{
    const int bh = blockIdx.x;            // 0..31 (fastest -> XCD locality)
    const int xp = blockIdx.y;            // 0..15
    const unsigned short* Qp  = qkv + (size_t)bh * N_ * HD_;
    const unsigned short* Kp  = qkv + RSZ + (size_t)bh * N_ * HD_;
    const unsigned short* Vtp = qkv + 2*RSZ + (size_t)bh * N_ * HD_;
    __shared__ unsigned short Ks[2][128][72], Vt[2][64][136];
    const int t = threadIdx.x;
    const int lane = t & 63, w = t >> 6;
    const int fr = lane & 15, fq = lane >> 4;
    const int srK = t >> 2, scK = (t & 3) * 16;    // K: 128 rows x 64 cols
    const int srV = t >> 3, scV = (t & 7) * 16;    // V^T: 64 rows x 128 cols
    const int qbase = (w < 4) ? ((31 - xp) * 64 + w * 16)
                              : (xp * 64 + (w - 4) * 16);
    const int KT = (33 - xp) >> 1;        // 128-wide tiles (heavy superset)
    const int ql = qbase + fr;            // this lane's q row
    const int lane_b0 = (2 * (fq & 1)) * 16 + fr;   // P-transport sources
    const int lane_b1 = lane_b0 + 16;
    const bool hi_sel = (fq >> 1) != 0;

    bf16x8 qfr[2];
    #pragma unroll
    for (int ks = 0; ks < 2; ++ks)
        qfr[ks] = *reinterpret_cast<const bf16x8*>(
            Qp + (size_t)ql * HD_ + ks*32 + fq*8);

    float m_run = -1e30f, l_run = 0.f;
    f32x4 o[4] = {};

    u16x8 kra = *reinterpret_cast<const u16x8*>(Kp + (size_t)srK * HD_ + scK);
    u16x8 krb = *reinterpret_cast<const u16x8*>(Kp + (size_t)srK * HD_ + scK + 8);
    u16x8 vra = *reinterpret_cast<const u16x8*>(Vtp + (size_t)srV * N_ + scV);
    u16x8 vrb = *reinterpret_cast<const u16x8*>(Vtp + (size_t)srV * N_ + scV + 8);

    for (int kt = 0; kt < KT; ++kt) {
        const int k0 = kt * 128;
        const int c = kt & 1;
        *reinterpret_cast<u16x8*>(&Ks[c][srK][scK])     = kra;
        *reinterpret_cast<u16x8*>(&Ks[c][srK][scK + 8]) = krb;
        *reinterpret_cast<u16x8*>(&Vt[c][srV][scV])     = vra;
        *reinterpret_cast<u16x8*>(&Vt[c][srV][scV + 8]) = vrb;
        __syncthreads();                  // single barrier per tile (dbuf)
        if (kt + 1 < KT) {                // prefetch next (hides under compute)
            const int kn = k0 + 128;
            kra = *reinterpret_cast<const u16x8*>(Kp + (size_t)(kn + srK) * HD_ + scK);
            krb = *reinterpret_cast<const u16x8*>(Kp + (size_t)(kn + srK) * HD_ + scK + 8);
            vra = *reinterpret_cast<const u16x8*>(Vtp + (size_t)srV * N_ + kn + scV);
            vrb = *reinterpret_cast<const u16x8*>(Vtp + (size_t)srV * N_ + kn + scV + 8);
        }
        if (k0 > qbase + 15) continue;    // fully masked for this wave

        // S^T = K Q^T: lane holds s[nf][r] = S[q=ql][k = k0+nf*16+fq*4+r]
        f32x4 s[8] = {};
        __builtin_amdgcn_s_setprio(1);
        #pragma unroll
        for (int ks = 0; ks < 2; ++ks) {
            #pragma unroll
            for (int nf = 0; nf < 8; ++nf) {
                bf16x8 bk = *reinterpret_cast<const bf16x8*>(&Ks[c][nf*16 + fr][ks*32 + fq*8]);
                s[nf] = MFMA16(bk, qfr[ks], s[nf]);
            }
        }
        __builtin_amdgcn_s_setprio(0);

        if (k0 + 127 > qbase) {           // diagonal region: causal mask
            #pragma unroll
            for (int nf = 0; nf < 8; ++nf)
                #pragma unroll
                for (int r = 0; r < 4; ++r)
                    if (k0 + nf*16 + fq*4 + r > ql) s[nf][r] = -1e30f;
        }

        // row max: v_max3 chain (T17) + 2 shfls
        float g[8];
        #pragma unroll
        for (int nf = 0; nf < 8; ++nf)
            g[nf] = fmaxf(max3f(s[nf][0], s[nf][1], s[nf][2]), s[nf][3]);
        float pm = max3f(max3f(g[0], g[1], g[2]),
                         max3f(g[3], g[4], g[5]),
                         fmaxf(g[6], g[7]));
        pm = fmaxf(pm, __shfl_xor(pm, 16));
        pm = fmaxf(pm, __shfl_xor(pm, 32));

        // defer-max (THR2 log2-units = 8 nats)
        const bool need = __any(pm > m_run + THR2);
        float scl = 1.f;
        if (need) {
            const float mnew = fmaxf(m_run, pm);
            scl = exp2i(m_run - mnew);
            m_run = mnew;
        }

        // P = 2^(s - m)  (scores pre-scaled by log2(e): single v_exp_f32)
        float rs = 0.f;
        unsigned int u[8][2];
        #pragma unroll
        for (int nf = 0; nf < 8; ++nf) {
            const float p0 = exp2i(s[nf][0] - m_run);
            const float p1 = exp2i(s[nf][1] - m_run);
            const float p2 = exp2i(s[nf][2] - m_run);
            const float p3 = exp2i(s[nf][3] - m_run);
            rs += (p0 + p1) + (p2 + p3);
            u[nf][0] = cvtpk(p0, p1);
            u[nf][1] = cvtpk(p2, p3);
        }
        {
            float v = rs;
            v += __shfl_xor(v, 16);
            v += __shfl_xor(v, 32);
            l_run = l_run * scl + v;
        }
        if (need) {
            #pragma unroll
            for (int df = 0; df < 4; ++df)
                #pragma unroll
                for (int r = 0; r < 4; ++r)
                    o[df][r] *= scl;
        }

        // P-transport: build PV B-frags pb[kk] (k = kk*32 + fq*8 + 0..7)
        bf16x8 pb[4];
        #pragma unroll
        for (int kk = 0; kk < 4; ++kk) {
            const unsigned int t00 = __shfl(u[2*kk+0][0], lane_b0);
            const unsigned int t01 = __shfl(u[2*kk+0][1], lane_b0);
            const unsigned int t02 = __shfl(u[2*kk+0][0], lane_b1);
            const unsigned int t03 = __shfl(u[2*kk+0][1], lane_b1);
            const unsigned int t10 = __shfl(u[2*kk+1][0], lane_b0);
            const unsigned int t11 = __shfl(u[2*kk+1][1], lane_b0);
            const unsigned int t12 = __shfl(u[2*kk+1][0], lane_b1);
            const unsigned int t13 = __shfl(u[2*kk+1][1], lane_b1);
            union { unsigned int wd[4]; bf16x8 v; } pu;
            pu.wd[0] = hi_sel ? t10 : t00;
            pu.wd[1] = hi_sel ? t11 : t01;
            pu.wd[2] = hi_sel ? t12 : t02;
            pu.wd[3] = hi_sel ? t13 : t03;
            pb[kk] = pu.v;
        }

        // O^T += V^T P^T
        __builtin_amdgcn_s_setprio(1);
        #pragma unroll
        for (int kk = 0; kk < 4; ++kk) {
            bf16x8 bv[4];
            #pragma unroll
            for (int df = 0; df < 4; ++df)
                bv[df] = *reinterpret_cast<const bf16x8*>(&Vt[c][df*16 + fr][kk*32 + fq*8]);
            #pragma unroll
            for (int df = 0; df < 4; ++df)
                o[df] = MFMA16(bv[df], pb[kk], o[df]);
        }
        __builtin_amdgcn_s_setprio(0);
    }

    // epilogue: lane holds O^T[d][q=ql], d = df*16 + fq*4 + r
    const int b = bh >> 4, h = bh & 15;
    const float inv = 1.0f / l_run;
    #pragma unroll
    for (int df = 0; df < 4; ++df)
        #pragma unroll
        for (int r = 0; r < 4; ++r) {
            const int d = df*16 + fq*4 + r;
            attn_out[((size_t)(b*N_ + ql))*E_ + h*64 + d] = f2bfu(o[df][r] * inv);
        }
}

// ---------------------------------------------------------------------------
// Kernel 3: out = attn @ Wo^T + bo — 64x128 tile glds engine (R11-proven).
// ---------------------------------------------------------------------------
__global__ __launch_bounds__(256) void out_glds_kernel(
    const unsigned short* __restrict__ A, const unsigned short* __restrict__ Wobf,
    const float* __restrict__ bo, float* __restrict__ out)
{
    const int m0 = blockIdx.x * 64;
    const int n0 = blockIdx.y * 128;
    __shared__ unsigned short ldsA[64*64];
    __shared__ unsigned short ldsB[128*64];
    const int t = threadIdx.x;
    const int lane = t & 63;
    const int w = t >> 6, wr = w >> 1, wc = w & 1;
    const int fr = lane & 15, fq = lane >> 4;
    const int subrow = lane >> 3;
    const int csw = ((lane & 7) ^ subrow) * 8;
    const int rcol = ((fq * 8) ^ ((fr & 7) * 8));
    f32x4 acc[2][4] = {};

    for (int kt = 0; kt < 16; ++kt) {
        const int k0 = kt * 64;
        __syncthreads();
        #pragma unroll
        for (int i = 0; i < 6; ++i) {
            const int c = w * 6 + i;
            if (c < 8) {
                const int row = c * 8 + subrow;
                gl_lds16(A + (size_t)(m0 + row) * E_ + k0 + csw, &ldsA[c * 512]);
            } else {
                const int row = (c - 8) * 8 + subrow;
                gl_lds16(Wobf + (size_t)(n0 + row) * E_ + k0 + csw, &ldsB[(c - 8) * 512]);
            }
        }
        __syncthreads();
        #pragma unroll
        for (int ks = 0; ks < 2; ++ks) {
            bf16x8 af[2], bfv[4];
            #pragma unroll
            for (int mf = 0; mf < 2; ++mf)
                af[mf] = *(const bf16x8*)&ldsA[(wr*32 + mf*16 + fr)*64 + (rcol ^ (ks*32))];
            #pragma unroll
            for (int nf = 0; nf < 4; ++nf)
                bfv[nf] = *(const bf16x8*)&ldsB[(wc*64 + nf*16 + fr)*64 + (rcol ^ (ks*32))];
            #pragma unroll
            for (int mf = 0; mf < 2; ++mf)
                #pragma unroll
                for (int nf = 0; nf < 4; ++nf)
                    acc[mf][nf] = MFMA16(af[mf], bfv[nf], acc[mf][nf]);
        }
    }

    #pragma unroll
    for (int mf = 0; mf < 2; ++mf) {
        #pragma unroll
        for (int r = 0; r < 4; ++r) {
            const int m = m0 + wr*32 + mf*16 + fq*4 + r;
            #pragma unroll
            for (int nf = 0; nf < 4; ++nf) {
                const int n = n0 + wc*64 + nf*16 + fr;
                out[(size_t)m * E_ + n] = acc[mf][nf][r] + bo[n];
            }
        }
    }
}

extern "C" void kernel_launch(void* const* d_in, const int* in_sizes, int n_in,
                              void* d_out, int out_size, void* d_ws, size_t ws_size,
                              hipStream_t stream) {
    const float* x  = (const float*)d_in[0];
    // d_in[1] = mask (causal tril, applied analytically)
    const float* Wq = (const float*)d_in[2];
    const float* Wk = (const float*)d_in[3];
    const float* Wv = (const float*)d_in[4];
    const float* Wo = (const float*)d_in[5];
    const float* bo = (const float*)d_in[6];
    float* out = (float*)d_out;

    unsigned short* ws = (unsigned short*)d_ws;
    const size_t need_main = 5 * RSZ * sizeof(unsigned short);   // 40 MB

    if (ws_size >= need_main) {
        unsigned short* xbf  = ws;
        unsigned short* wbf  = ws + RSZ;
        unsigned short* qkvq = ws + 2 * RSZ;          // Q,K,Vt contiguous
        unsigned short* attn_ws = ws;                 // over xbf (dead)
        unsigned short* wobf = wbf + 3 * (size_t)E_ * E_;

        fconv_all_kernel<<<4096, 256, 0, stream>>>(x, Wq, Wk, Wv, Wo, xbf, wbf);

        dim3 g1(M_ / 64, E_ / 128);                   // m fastest: XCD locality
        qkv_fused_kernel<<<g1, 256, 0, stream>>>(xbf, wbf, qkvq);

        dim3 g2(B_ * H_, 16);                         // bh fastest: XCD locality
        attn_mfma_kernel<<<g2, 512, 0, stream>>>(qkvq, attn_ws);

        dim3 g3(M_ / 64, E_ / 128);
        out_glds_kernel<<<g3, 256, 0, stream>>>(attn_ws, wobf, bo, out);
    } else {
        unsigned short* wbf = ws;
        unsigned short* qkvq = ws + RSZ;
        unsigned short* attn_ws = ws;
        unsigned short* wobf = ws + RSZ;

        const int cgrid = E_ * E_ / (256 * 8);
        fconv_kernel<<<cgrid, 256, 0, stream>>>(Wq, wbf);
        fconv_kernel<<<cgrid, 256, 0, stream>>>(Wk, wbf + (size_t)E_ * E_);
        fconv_kernel<<<cgrid, 256, 0, stream>>>(Wv, wbf + 2 * (size_t)E_ * E_);

        dim3 g1(M_ / 128, E_ / 128, 3);
        qkv_f32_kernel<<<g1, 256, 0, stream>>>(x, wbf, qkvq);

        dim3 g2(B_ * H_, 16);
        attn_mfma_kernel<<<g2, 512, 0, stream>>>(qkvq, attn_ws);

        fconv_kernel<<<cgrid, 256, 0, stream>>>(Wo, wobf);

        dim3 g3(M_ / 64, E_ / 128);
        out_glds_kernel<<<g3, 256, 0, stream>>>(attn_ws, wobf, bo, out);
    }
}

// Round 23
// 103.817 us; speedup vs baseline: 1.1016x; 1.1016x over previous
//
#include <hip/hip_runtime.h>
#include <hip/hip_bf16.h>

#define B_  2
#define N_  2048
#define E_  1024
#define H_  16
#define HD_ 64
#define M_  (B_*N_)
#define RSZ ((size_t)M_ * E_)          // one ws region, u16 elems (8 MB)

// Q pre-scale: 1/sqrt(64) * log2(e)  -> scores land in log2 domain
#define QSCALE 0.18033688f
// defer-max threshold in log2 units (= 8 nats)
#define THR2   11.5416f

typedef short bf16x8 __attribute__((ext_vector_type(8)));
typedef float f32x4 __attribute__((ext_vector_type(4)));
typedef unsigned short u16x8 __attribute__((ext_vector_type(8)));

#define AS1 __attribute__((address_space(1)))
#define AS3 __attribute__((address_space(3)))

__device__ __forceinline__ unsigned short f2bfu(float f) {
    __hip_bfloat16 h = __float2bfloat16(f);
    return *reinterpret_cast<unsigned short*>(&h);
}
__device__ __forceinline__ unsigned int cvtpk(float lo, float hi) {
    unsigned int r;
    asm("v_cvt_pk_bf16_f32 %0, %1, %2" : "=v"(r) : "v"(lo), "v"(hi));
    return r;
}
__device__ __forceinline__ float exp2i(float x) {   // 2^x, single v_exp_f32
    float r;
    asm("v_exp_f32 %0, %1" : "=v"(r) : "v"(x));
    return r;
}
__device__ __forceinline__ float max3f(float a, float b, float c) {
    float r;
    asm("v_max3_f32 %0, %1, %2, %3" : "=v"(r) : "v"(a), "v"(b), "v"(c));
    return r;
}
#define MFMA16(a,b,c) __builtin_amdgcn_mfma_f32_16x16x32_bf16((a),(b),(c),0,0,0)

__device__ __forceinline__ void gl_lds16(const void* g, void* l) {
    __builtin_amdgcn_global_load_lds((const AS1 void*)g, (AS3 void*)l, 16, 0, 0);
}

// ---------------------------------------------------------------------------
// Kernel 0a: fused fp32->bf16 conversion for x + Wq,Wk,Wv,Wo in ONE launch.
// ---------------------------------------------------------------------------
__global__ __launch_bounds__(256) void fconv_all_kernel(
    const float* __restrict__ x,
    const float* __restrict__ Wq, const float* __restrict__ Wk,
    const float* __restrict__ Wv, const float* __restrict__ Wo,
    unsigned short* __restrict__ xbf, unsigned short* __restrict__ wbf)
{
    const int bid = blockIdx.x;
    const float* src;
    unsigned short* dst;
    int off;
    if (bid < 2048) {
        src = x; dst = xbf; off = bid * 2048 + threadIdx.x * 8;
    } else {
        const int z = (bid - 2048) >> 9;             // 0..3
        src = (z == 0) ? Wq : (z == 1 ? Wk : (z == 2 ? Wv : Wo));
        dst = wbf + (size_t)z * E_ * E_;
        off = ((bid - 2048) & 511) * 2048 + threadIdx.x * 8;
    }
    const float4 a = *reinterpret_cast<const float4*>(src + off);
    const float4 b = *reinterpret_cast<const float4*>(src + off + 4);
    u16x8 v;
    v[0]=f2bfu(a.x); v[1]=f2bfu(a.y); v[2]=f2bfu(a.z); v[3]=f2bfu(a.w);
    v[4]=f2bfu(b.x); v[5]=f2bfu(b.y); v[6]=f2bfu(b.z); v[7]=f2bfu(b.w);
    *reinterpret_cast<u16x8*>(dst + off) = v;
}

// Kernel 0b: single-source conversion (fallback path only)
__global__ __launch_bounds__(256) void fconv_kernel(
    const float* __restrict__ src, unsigned short* __restrict__ dst)
{
    const int i0 = (blockIdx.x * 256 + threadIdx.x) * 8;
    const float4 a = *reinterpret_cast<const float4*>(src + i0);
    const float4 b = *reinterpret_cast<const float4*>(src + i0 + 4);
    u16x8 v;
    v[0]=f2bfu(a.x); v[1]=f2bfu(a.y); v[2]=f2bfu(a.z); v[3]=f2bfu(a.w);
    v[4]=f2bfu(b.x); v[5]=f2bfu(b.y); v[6]=f2bfu(b.z); v[7]=f2bfu(b.w);
    *reinterpret_cast<u16x8*>(dst + i0) = v;
}

// ---------------------------------------------------------------------------
// Kernel 1a (main): Z-FUSED QKV projection (R12/R20-proven). A(x) staged
// once via glds (coalesced), 3 B tiles, 48 MFMA/wave/K-step. LDS 56 KB.
// Single-buffered glds, XOR swizzle. Q pre-scaled by QSCALE (log2-domain).
// z==2 writes V^T.
// ---------------------------------------------------------------------------
__global__ __launch_bounds__(256) void qkv_fused_kernel(
    const unsigned short* __restrict__ xbf, const unsigned short* __restrict__ wbf,
    unsigned short* __restrict__ qkv)
{
    const int m0 = blockIdx.x * 64;
    const int n0 = blockIdx.y * 128;
    __shared__ unsigned short ldsA[64*64];        // 8 KB
    __shared__ unsigned short ldsB[3][128*64];    // 48 KB
    const int t = threadIdx.x;
    const int lane = t & 63;
    const int w = t >> 6, wr = w >> 1, wc = w & 1;
    const int fr = lane & 15, fq = lane >> 4;
    const int subrow = lane >> 3;                    // 0..7
    const int csw = ((lane & 7) ^ subrow) * 8;       // inverse-swizzled src col
    const int rcol = ((fq * 8) ^ ((fr & 7) * 8));    // swizzled read col (ks=0)
    f32x4 acc[3][2][4] = {};

    for (int kt = 0; kt < 16; ++kt) {
        const int k0 = kt * 64;
        __syncthreads();                             // prev compute done
        #pragma unroll
        for (int i = 0; i < 14; ++i) {               // 56 chunks over 4 waves
            const int c = w * 14 + i;
            if (c < 8) {                             // A: chunk c
                const int row = c * 8 + subrow;
                gl_lds16(xbf + (size_t)(m0 + row) * E_ + k0 + csw, &ldsA[c * 512]);
            } else {                                 // B: z = (c-8)/16
                const int cc = c - 8;
                const int zb = cc >> 4, bc = cc & 15;
                const int row = bc * 8 + subrow;
                gl_lds16(wbf + (size_t)zb * E_ * E_ + (size_t)(n0 + row) * E_ + k0 + csw,
                         &ldsB[zb][bc * 512]);
            }
        }
        __syncthreads();                             // stage visible
        #pragma unroll
        for (int ks = 0; ks < 2; ++ks) {
            bf16x8 af[2];
            #pragma unroll
            for (int mf = 0; mf < 2; ++mf)
                af[mf] = *(const bf16x8*)&ldsA[(wr*32 + mf*16 + fr)*64 + (rcol ^ (ks*32))];
            #pragma unroll
            for (int zb = 0; zb < 3; ++zb) {
                bf16x8 bfv[4];
                #pragma unroll
                for (int nf = 0; nf < 4; ++nf)
                    bfv[nf] = *(const bf16x8*)&ldsB[zb][(wc*64 + nf*16 + fr)*64 + (rcol ^ (ks*32))];
                #pragma unroll
                for (int mf = 0; mf < 2; ++mf)
                    #pragma unroll
                    for (int nf = 0; nf < 4; ++nf)
                        acc[zb][mf][nf] = MFMA16(af[mf], bfv[nf], acc[zb][mf][nf]);
            }
        }
    }

    #pragma unroll
    for (int zb = 0; zb < 3; ++zb) {
        unsigned short* __restrict__ out = qkv + (size_t)zb * RSZ;
        const float scale = (zb == 0) ? QSCALE : 1.0f;
        #pragma unroll
        for (int mf = 0; mf < 2; ++mf) {
            #pragma unroll
            for (int r = 0; r < 4; ++r) {
                const int m = m0 + wr*32 + mf*16 + fq*4 + r;
                const int b = m >> 11, npos = m & (N_ - 1);
                #pragma unroll
                for (int nf = 0; nf < 4; ++nf) {
                    const int n = n0 + wc*64 + nf*16 + fr;
                    const int h = n >> 6, d = n & 63;
                    const unsigned short val = f2bfu(acc[zb][mf][nf][r] * scale);
                    if (zb == 2)   // V^T: [bh][d][npos]
                        out[(((size_t)(b*H_ + h))*HD_ + d)*N_ + npos] = val;
                    else
                        out[(((size_t)(b*H_ + h))*N_ + npos)*HD_ + d] = val;
                }
            }
        }
    }
}

// ---------------------------------------------------------------------------
// Kernel 1b (fallback): QKV with fp32 x converted at staging (reg-staged).
// ---------------------------------------------------------------------------
__global__ __launch_bounds__(256) void qkv_f32_kernel(
    const float* __restrict__ x, const unsigned short* __restrict__ wbf,
    unsigned short* __restrict__ qkv)
{
    const int z = blockIdx.z;
    const unsigned short* __restrict__ W = wbf + (size_t)z * E_ * E_;
    unsigned short* __restrict__ out = qkv + (size_t)z * RSZ;
    const int m0 = blockIdx.x * 128;
    const int n0 = blockIdx.y * 128;
    __shared__ unsigned short As[128][72];
    __shared__ unsigned short Bs[128][72];
    const int t = threadIdx.x;
    const int lane = t & 63;
    const int w = t >> 6, wr = w >> 1, wc = w & 1;
    const int fr = lane & 15, fq = lane >> 4;
    const int srow = t >> 1, scol = (t & 1) * 32;
    f32x4 acc[4][4] = {};

    const float* arow = x + (size_t)(m0 + srow) * E_ + scol;
    const unsigned short* brow = W + (size_t)(n0 + srow) * E_ + scol;

    float4 a4[8];
    u16x8 b8[4];
    #pragma unroll
    for (int i = 0; i < 8; ++i) a4[i] = reinterpret_cast<const float4*>(arow)[i];
    #pragma unroll
    for (int i = 0; i < 4; ++i) b8[i] = reinterpret_cast<const u16x8*>(brow)[i];

    for (int k0 = 0; k0 < E_; k0 += 64) {
        __syncthreads();
        #pragma unroll
        for (int j = 0; j < 4; ++j) {
            u16x8 va;
            va[0]=f2bfu(a4[2*j].x); va[1]=f2bfu(a4[2*j].y); va[2]=f2bfu(a4[2*j].z); va[3]=f2bfu(a4[2*j].w);
            va[4]=f2bfu(a4[2*j+1].x); va[5]=f2bfu(a4[2*j+1].y); va[6]=f2bfu(a4[2*j+1].z); va[7]=f2bfu(a4[2*j+1].w);
            *reinterpret_cast<u16x8*>(&As[srow][scol + 8*j]) = va;
            *reinterpret_cast<u16x8*>(&Bs[srow][scol + 8*j]) = b8[j];
        }
        __syncthreads();
        if (k0 + 64 < E_) {
            #pragma unroll
            for (int i = 0; i < 8; ++i)
                a4[i] = reinterpret_cast<const float4*>(arow + k0 + 64)[i];
            #pragma unroll
            for (int i = 0; i < 4; ++i)
                b8[i] = reinterpret_cast<const u16x8*>(brow + k0 + 64)[i];
        }
        #pragma unroll
        for (int ks = 0; ks < 2; ++ks) {
            bf16x8 af[4], bfv[4];
            #pragma unroll
            for (int mf = 0; mf < 4; ++mf)
                af[mf] = *reinterpret_cast<const bf16x8*>(&As[wr*64 + mf*16 + fr][ks*32 + fq*8]);
            #pragma unroll
            for (int nf = 0; nf < 4; ++nf)
                bfv[nf] = *reinterpret_cast<const bf16x8*>(&Bs[wc*64 + nf*16 + fr][ks*32 + fq*8]);
            #pragma unroll
            for (int mf = 0; mf < 4; ++mf)
                #pragma unroll
                for (int nf = 0; nf < 4; ++nf)
                    acc[mf][nf] = MFMA16(af[mf], bfv[nf], acc[mf][nf]);
        }
    }

    const float scale = (z == 0) ? QSCALE : 1.0f;
    #pragma unroll
    for (int mf = 0; mf < 4; ++mf) {
        #pragma unroll
        for (int r = 0; r < 4; ++r) {
            const int m = m0 + wr*64 + mf*16 + fq*4 + r;
            const int b = m >> 11, npos = m & (N_ - 1);
            #pragma unroll
            for (int nf = 0; nf < 4; ++nf) {
                const int n = n0 + wc*64 + nf*16 + fr;
                const int h = n >> 6, d = n & 63;
                const unsigned short val = f2bfu(acc[mf][nf][r] * scale);
                if (z == 2)
                    out[(((size_t)(b*H_ + h))*HD_ + d)*N_ + npos] = val;
                else
                    out[(((size_t)(b*H_ + h))*N_ + npos)*HD_ + d] = val;
            }
        }
    }
}

// ---------------------------------------------------------------------------
// Kernel 2: MFMA flash attention — R19/R20 structure (dbuf, 1 barrier/tile,
// pairing, exp2-domain softmax, max3 row-max). Unchanged.
// ---------------------------------------------------------------------------
__global__ __launch_bounds__(512) void attn_mfma_kernel(
    const unsigned short* __restrict__ qkv, unsigned short* __restrict__ attn_out)
{
    const int bh = blockIdx.x;            // 0..31 (fastest -> XCD locality)
    const int xp = blockIdx.y;            // 0..15
    const unsigned short* Qp  = qkv + (size_t)bh * N_ * HD_;
    const unsigned short* Kp  = qkv + RSZ + (size_t)bh * N_ * HD_;
    const unsigned short* Vtp = qkv + 2*RSZ + (size_t)bh * N_ * HD_;
    __shared__ unsigned short Ks[2][128][72], Vt[2][64][136];
    const int t = threadIdx.x;
    const int lane = t & 63, w = t >> 6;
    const int fr = lane & 15, fq = lane >> 4;
    const int srK = t >> 2, scK = (t & 3) * 16;    // K: 128 rows x 64 cols
    const int srV = t >> 3, scV = (t & 7) * 16;    // V^T: 64 rows x 128 cols
    const int qbase = (w < 4) ? ((31 - xp) * 64 + w * 16)
                              : (xp * 64 + (w - 4) * 16);
    const int KT = (33 - xp) >> 1;        // 128-wide tiles (heavy superset)
    const int ql = qbase + fr;            // this lane's q row
    const int lane_b0 = (2 * (fq & 1)) * 16 + fr;   // P-transport sources
    const int lane_b1 = lane_b0 + 16;
    const bool hi_sel = (fq >> 1) != 0;

    bf16x8 qfr[2];
    #pragma unroll
    for (int ks = 0; ks < 2; ++ks)
        qfr[ks] = *reinterpret_cast<const bf16x8*>(
            Qp + (size_t)ql * HD_ + ks*32 + fq*8);

    float m_run = -1e30f, l_run = 0.f;
    f32x4 o[4] = {};

    u16x8 kra = *reinterpret_cast<const u16x8*>(Kp + (size_t)srK * HD_ + scK);
    u16x8 krb = *reinterpret_cast<const u16x8*>(Kp + (size_t)srK * HD_ + scK + 8);
    u16x8 vra = *reinterpret_cast<const u16x8*>(Vtp + (size_t)srV * N_ + scV);
    u16x8 vrb = *reinterpret_cast<const u16x8*>(Vtp + (size_t)srV * N_ + scV + 8);

    for (int kt = 0; kt < KT; ++kt) {
        const int k0 = kt * 128;
        const int c = kt & 1;
        *reinterpret_cast<u16x8*>(&Ks[c][srK][scK])     = kra;
        *reinterpret_cast<u16x8*>(&Ks[c][srK][scK + 8]) = krb;
        *reinterpret_cast<u16x8*>(&Vt[c][srV][scV])     = vra;
        *reinterpret_cast<u16x8*>(&Vt[c][srV][scV + 8]) = vrb;
        __syncthreads();                  // single barrier per tile (dbuf)
        if (kt + 1 < KT) {                // prefetch next (hides under compute)
            const int kn = k0 + 128;
            kra = *reinterpret_cast<const u16x8*>(Kp + (size_t)(kn + srK) * HD_ + scK);
            krb = *reinterpret_cast<const u16x8*>(Kp + (size_t)(kn + srK) * HD_ + scK + 8);
            vra = *reinterpret_cast<const u16x8*>(Vtp + (size_t)srV * N_ + kn + scV);
            vrb = *reinterpret_cast<const u16x8*>(Vtp + (size_t)srV * N_ + kn + scV + 8);
        }
        if (k0 > qbase + 15) continue;    // fully masked for this wave

        // S^T = K Q^T: lane holds s[nf][r] = S[q=ql][k = k0+nf*16+fq*4+r]
        f32x4 s[8] = {};
        __builtin_amdgcn_s_setprio(1);
        #pragma unroll
        for (int ks = 0; ks < 2; ++ks) {
            #pragma unroll
            for (int nf = 0; nf < 8; ++nf) {
                bf16x8 bk = *reinterpret_cast<const bf16x8*>(&Ks[c][nf*16 + fr][ks*32 + fq*8]);
                s[nf] = MFMA16(bk, qfr[ks], s[nf]);
            }
        }
        __builtin_amdgcn_s_setprio(0);

        if (k0 + 127 > qbase) {           // diagonal region: causal mask
            #pragma unroll
            for (int nf = 0; nf < 8; ++nf)
                #pragma unroll
                for (int r = 0; r < 4; ++r)
                    if (k0 + nf*16 + fq*4 + r > ql) s[nf][r] = -1e30f;
        }

        // row max: v_max3 chain (T17) + 2 shfls
        float g[8];
        #pragma unroll
        for (int nf = 0; nf < 8; ++nf)
            g[nf] = fmaxf(max3f(s[nf][0], s[nf][1], s[nf][2]), s[nf][3]);
        float pm = max3f(max3f(g[0], g[1], g[2]),
                         max3f(g[3], g[4], g[5]),
                         fmaxf(g[6], g[7]));
        pm = fmaxf(pm, __shfl_xor(pm, 16));
        pm = fmaxf(pm, __shfl_xor(pm, 32));

        // defer-max (THR2 log2-units = 8 nats)
        const bool need = __any(pm > m_run + THR2);
        float scl = 1.f;
        if (need) {
            const float mnew = fmaxf(m_run, pm);
            scl = exp2i(m_run - mnew);
            m_run = mnew;
        }

        // P = 2^(s - m)  (scores pre-scaled by log2(e): single v_exp_f32)
        float rs = 0.f;
        unsigned int u[8][2];
        #pragma unroll
        for (int nf = 0; nf < 8; ++nf) {
            const float p0 = exp2i(s[nf][0] - m_run);
            const float p1 = exp2i(s[nf][1] - m_run);
            const float p2 = exp2i(s[nf][2] - m_run);
            const float p3 = exp2i(s[nf][3] - m_run);
            rs += (p0 + p1) + (p2 + p3);
            u[nf][0] = cvtpk(p0, p1);
            u[nf][1] = cvtpk(p2, p3);
        }
        {
            float v = rs;
            v += __shfl_xor(v, 16);
            v += __shfl_xor(v, 32);
            l_run = l_run * scl + v;
        }
        if (need) {
            #pragma unroll
            for (int df = 0; df < 4; ++df)
                #pragma unroll
                for (int r = 0; r < 4; ++r)
                    o[df][r] *= scl;
        }

        // P-transport: build PV B-frags pb[kk] (k = kk*32 + fq*8 + 0..7)
        bf16x8 pb[4];
        #pragma unroll
        for (int kk = 0; kk < 4; ++kk) {
            const unsigned int t00 = __shfl(u[2*kk+0][0], lane_b0);
            const unsigned int t01 = __shfl(u[2*kk+0][1], lane_b0);
            const unsigned int t02 = __shfl(u[2*kk+0][0], lane_b1);
            const unsigned int t03 = __shfl(u[2*kk+0][1], lane_b1);
            const unsigned int t10 = __shfl(u[2*kk+1][0], lane_b0);
            const unsigned int t11 = __shfl(u[2*kk+1][1], lane_b0);
            const unsigned int t12 = __shfl(u[2*kk+1][0], lane_b1);
            const unsigned int t13 = __shfl(u[2*kk+1][1], lane_b1);
            union { unsigned int wd[4]; bf16x8 v; } pu;
            pu.wd[0] = hi_sel ? t10 : t00;
            pu.wd[1] = hi_sel ? t11 : t01;
            pu.wd[2] = hi_sel ? t12 : t02;
            pu.wd[3] = hi_sel ? t13 : t03;
            pb[kk] = pu.v;
        }

        // O^T += V^T P^T
        __builtin_amdgcn_s_setprio(1);
        #pragma unroll
        for (int kk = 0; kk < 4; ++kk) {
            bf16x8 bv[4];
            #pragma unroll
            for (int df = 0; df < 4; ++df)
                bv[df] = *reinterpret_cast<const bf16x8*>(&Vt[c][df*16 + fr][kk*32 + fq*8]);
            #pragma unroll
            for (int df = 0; df < 4; ++df)
                o[df] = MFMA16(bv[df], pb[kk], o[df]);
        }
        __builtin_amdgcn_s_setprio(0);
    }

    // epilogue: lane holds O^T[d][q=ql], d = df*16 + fq*4 + r
    const int b = bh >> 4, h = bh & 15;
    const float inv = 1.0f / l_run;
    #pragma unroll
    for (int df = 0; df < 4; ++df)
        #pragma unroll
        for (int r = 0; r < 4; ++r) {
            const int d = df*16 + fq*4 + r;
            attn_out[((size_t)(b*N_ + ql))*E_ + h*64 + d] = f2bfu(o[df][r] * inv);
        }
}

// ---------------------------------------------------------------------------
// Kernel 3: out = attn @ Wo^T + bo — 64x128 tile glds engine (R11-proven).
// ---------------------------------------------------------------------------
__global__ __launch_bounds__(256) void out_glds_kernel(
    const unsigned short* __restrict__ A, const unsigned short* __restrict__ Wobf,
    const float* __restrict__ bo, float* __restrict__ out)
{
    const int m0 = blockIdx.x * 64;
    const int n0 = blockIdx.y * 128;
    __shared__ unsigned short ldsA[64*64];
    __shared__ unsigned short ldsB[128*64];
    const int t = threadIdx.x;
    const int lane = t & 63;
    const int w = t >> 6, wr = w >> 1, wc = w & 1;
    const int fr = lane & 15, fq = lane >> 4;
    const int subrow = lane >> 3;
    const int csw = ((lane & 7) ^ subrow) * 8;
    const int rcol = ((fq * 8) ^ ((fr & 7) * 8));
    f32x4 acc[2][4] = {};

    for (int kt = 0; kt < 16; ++kt) {
        const int k0 = kt * 64;
        __syncthreads();
        #pragma unroll
        for (int i = 0; i < 6; ++i) {
            const int c = w * 6 + i;
            if (c < 8) {
                const int row = c * 8 + subrow;
                gl_lds16(A + (size_t)(m0 + row) * E_ + k0 + csw, &ldsA[c * 512]);
            } else {
                const int row = (c - 8) * 8 + subrow;
                gl_lds16(Wobf + (size_t)(n0 + row) * E_ + k0 + csw, &ldsB[(c - 8) * 512]);
            }
        }
        __syncthreads();
        #pragma unroll
        for (int ks = 0; ks < 2; ++ks) {
            bf16x8 af[2], bfv[4];
            #pragma unroll
            for (int mf = 0; mf < 2; ++mf)
                af[mf] = *(const bf16x8*)&ldsA[(wr*32 + mf*16 + fr)*64 + (rcol ^ (ks*32))];
            #pragma unroll
            for (int nf = 0; nf < 4; ++nf)
                bfv[nf] = *(const bf16x8*)&ldsB[(wc*64 + nf*16 + fr)*64 + (rcol ^ (ks*32))];
            #pragma unroll
            for (int mf = 0; mf < 2; ++mf)
                #pragma unroll
                for (int nf = 0; nf < 4; ++nf)
                    acc[mf][nf] = MFMA16(af[mf], bfv[nf], acc[mf][nf]);
        }
    }

    #pragma unroll
    for (int mf = 0; mf < 2; ++mf) {
        #pragma unroll
        for (int r = 0; r < 4; ++r) {
            const int m = m0 + wr*32 + mf*16 + fq*4 + r;
            #pragma unroll
            for (int nf = 0; nf < 4; ++nf) {
                const int n = n0 + wc*64 + nf*16 + fr;
                out[(size_t)m * E_ + n] = acc[mf][nf][r] + bo[n];
            }
        }
    }
}

extern "C" void kernel_launch(void* const* d_in, const int* in_sizes, int n_in,
                              void* d_out, int out_size, void* d_ws, size_t ws_size,
                              hipStream_t stream) {
    const float* x  = (const float*)d_in[0];
    // d_in[1] = mask (causal tril, applied analytically)
    const float* Wq = (const float*)d_in[2];
    const float* Wk = (const float*)d_in[3];
    const float* Wv = (const float*)d_in[4];
    const float* Wo = (const float*)d_in[5];
    const float* bo = (const float*)d_in[6];
    float* out = (float*)d_out;

    unsigned short* ws = (unsigned short*)d_ws;
    const size_t need_main = 5 * RSZ * sizeof(unsigned short);   // 40 MB

    if (ws_size >= need_main) {
        unsigned short* xbf  = ws;
        unsigned short* wbf  = ws + RSZ;
        unsigned short* qkvq = ws + 2 * RSZ;          // Q,K,Vt contiguous
        unsigned short* attn_ws = ws;                 // over xbf (dead)
        unsigned short* wobf = wbf + 3 * (size_t)E_ * E_;

        fconv_all_kernel<<<4096, 256, 0, stream>>>(x, Wq, Wk, Wv, Wo, xbf, wbf);

        dim3 g1(M_ / 64, E_ / 128);                   // m fastest: XCD locality
        qkv_fused_kernel<<<g1, 256, 0, stream>>>(xbf, wbf, qkvq);

        dim3 g2(B_ * H_, 16);                         // bh fastest: XCD locality
        attn_mfma_kernel<<<g2, 512, 0, stream>>>(qkvq, attn_ws);

        dim3 g3(M_ / 64, E_ / 128);
        out_glds_kernel<<<g3, 256, 0, stream>>>(attn_ws, wobf, bo, out);
    } else {
        unsigned short* wbf = ws;
        unsigned short* qkvq = ws + RSZ;
        unsigned short* attn_ws = ws;
        unsigned short* wobf = ws + RSZ;

        const int cgrid = E_ * E_ / (256 * 8);
        fconv_kernel<<<cgrid, 256, 0, stream>>>(Wq, wbf);
        fconv_kernel<<<cgrid, 256, 0, stream>>>(Wk, wbf + (size_t)E_ * E_);
        fconv_kernel<<<cgrid, 256, 0, stream>>>(Wv, wbf + 2 * (size_t)E_ * E_);

        dim3 g1(M_ / 128, E_ / 128, 3);
        qkv_f32_kernel<<<g1, 256, 0, stream>>>(x, wbf, qkvq);

        dim3 g2(B_ * H_, 16);
        attn_mfma_kernel<<<g2, 512, 0, stream>>>(qkvq, attn_ws);

        fconv_kernel<<<cgrid, 256, 0, stream>>>(Wo, wobf);

        dim3 g3(M_ / 64, E_ / 128);
        out_glds_kernel<<<g3, 256, 0, stream>>>(attn_ws, wobf, bo, out);
    }
}